// Round 5
// baseline (373.724 us; speedup 1.0000x reference)
//
#include <hip/hip_runtime.h>
#include <hip/hip_bf16.h>
#include <cstdint>
#include <cstddef>

// MoE: T=4096, D=1024, H=2816, E=8, top-2, SwiGLU.
// R5: R4's 8-phase pipeline with ALL sched_barrier(0) removed (m141: full
//     order-pinning caps GEMMs at ~510 TF; ordering is already guaranteed by
//     side-effecting gload_lds/s_barrier + memory-clobber vmcnt asm + data deps).

#define Tt 4096
#define Dd 1024
#define Hh 2816
#define Ee 8
#define NVT 39  // max sum_e ceil(ne/256)

typedef __bf16 bf16_t;
typedef __bf16 bf16x4 __attribute__((ext_vector_type(4)));
typedef __bf16 bf16x8 __attribute__((ext_vector_type(8)));
typedef float f32x4 __attribute__((ext_vector_type(4)));

__device__ __forceinline__ void gload16(const void* g, void* l) {
  __builtin_amdgcn_global_load_lds(
      (__attribute__((address_space(1))) void*)(void*)(uintptr_t)g,
      (__attribute__((address_space(3))) void*)l, 16, 0, 0);
}
#define WAIT_VM(N) asm volatile("s_waitcnt vmcnt(" #N ")" ::: "memory")
#define BAR() __builtin_amdgcn_s_barrier()

// ---------------- gate: fp32 logits, top-2, softmax, routing, + x->bf16 -----
__global__ __launch_bounds__(256) void gate_kernel(
    const float* __restrict__ x, const float* __restrict__ gw_g,
    int* __restrict__ counts, int* __restrict__ perm, float* __restrict__ topkw,
    bf16_t* __restrict__ xb) {
  __shared__ float gw[Dd * 9];
  const int tid = threadIdx.x;
  for (int i = tid; i < Dd * Ee; i += 256) gw[(i >> 3) * 9 + (i & 7)] = gw_g[i];
  __syncthreads();
  const int tok = blockIdx.x * 32 + (tid >> 3);
  const int part = tid & 7;
  const float* xr = x + (size_t)tok * Dd;
  float acc[Ee];
#pragma unroll
  for (int e = 0; e < Ee; ++e) acc[e] = 0.f;
  for (int i = 0; i < 32; ++i) {
    const int d = i * 32 + part * 4;
    const float4 xv = *(const float4*)(xr + d);
    bf16x4 bv; bv[0] = (__bf16)xv.x; bv[1] = (__bf16)xv.y; bv[2] = (__bf16)xv.z; bv[3] = (__bf16)xv.w;
    *(bf16x4*)(xb + (size_t)tok * Dd + d) = bv;
    const float xs[4] = {xv.x, xv.y, xv.z, xv.w};
#pragma unroll
    for (int j = 0; j < 4; ++j)
#pragma unroll
      for (int e = 0; e < Ee; ++e) acc[e] += xs[j] * gw[(d + j) * 9 + e];
  }
#pragma unroll
  for (int s = 1; s < 8; s <<= 1)
#pragma unroll
    for (int e = 0; e < Ee; ++e) acc[e] += __shfl_xor(acc[e], s, 64);
  if (part == 0) {
    int i0 = 0; float v0 = acc[0];
#pragma unroll
    for (int e = 1; e < Ee; ++e) if (acc[e] > v0) { v0 = acc[e]; i0 = e; }
    int i1 = -1; float v1 = -1e30f;
#pragma unroll
    for (int e = 0; e < Ee; ++e)
      if (e != i0 && acc[e] > v1) { v1 = acc[e]; i1 = e; }
    const float w0 = 1.f / (1.f + __expf(v1 - v0));
    topkw[tok * 2 + 0] = w0;
    topkw[tok * 2 + 1] = 1.f - w0;
    const int p0 = atomicAdd(&counts[i0], 1);
    perm[i0 * Tt + p0] = tok * 2 + 0;
    const int p1 = atomicAdd(&counts[i1], 1);
    perm[i1 * Tt + p1] = tok * 2 + 1;
  }
}

__global__ void scan_kernel(const int* __restrict__ counts, int* __restrict__ offs,
                            int* __restrict__ ts) {
  if (threadIdx.x == 0) {
    int s = 0, t = 0;
    for (int e = 0; e < Ee; ++e) {
      offs[e] = s; ts[e] = t;
      s += counts[e]; t += (counts[e] + 255) >> 8;
    }
    offs[Ee] = s; ts[Ee] = t;
  }
}

// ---------------- transpose + cast weights to bf16 (k-contiguous) ----------
__global__ __launch_bounds__(256) void prep_w_kernel(
    const float* __restrict__ w1, const float* __restrict__ w3,
    const float* __restrict__ w2, bf16_t* __restrict__ w1t,
    bf16_t* __restrict__ w3t, bf16_t* __restrict__ w2t) {
  int bid = blockIdx.x;
  const int ntile = Ee * (Dd / 64) * (Hh / 64);
  const float* src; bf16_t* dst; int R, C;
  if (bid < ntile) { src = w1; dst = w1t; R = Dd; C = Hh; }
  else if (bid < 2 * ntile) { src = w3; dst = w3t; R = Dd; C = Hh; bid -= ntile; }
  else { src = w2; dst = w2t; R = Hh; C = Dd; bid -= 2 * ntile; }
  const int tilesC = C / 64, tilesR = R / 64;
  const int e = bid / (tilesR * tilesC);
  const int rem = bid % (tilesR * tilesC);
  const int r0 = (rem / tilesC) * 64, c0 = (rem % tilesC) * 64;
  src += (size_t)e * R * C;
  dst += (size_t)e * R * C;

  __shared__ bf16_t tile[64 * 68];
  const int tid = threadIdx.x;
#pragma unroll
  for (int i = 0; i < 16; ++i) {
    const int r = (tid >> 6) + i * 4;
    const int c = tid & 63;
    tile[c * 68 + r] = (__bf16)src[(size_t)(r0 + r) * C + c0 + c];
  }
  __syncthreads();
#pragma unroll
  for (int i = 0; i < 4; ++i) {
    const int c = i * 16 + (tid >> 4);
    const int rch = (tid & 15) * 4;
    uint2 val;
    val.x = *(const uint32_t*)(tile + c * 68 + rch);
    val.y = *(const uint32_t*)(tile + c * 68 + rch + 2);
    *(uint2*)(dst + (size_t)(c0 + c) * R + r0 + rch) = val;
  }
}

// ---------------- FFN1: h = silu(X@W1) * (X@W3), 256 x (128h stacked) ------
__global__ __launch_bounds__(512, 2) void ffn1_kernel(
    const bf16_t* __restrict__ xb, const bf16_t* __restrict__ w1t,
    const bf16_t* __restrict__ w3t, const int* __restrict__ perm,
    const int* __restrict__ counts, const int* __restrict__ offs,
    const int* __restrict__ ts, bf16_t* __restrict__ hbuf) {
  const int G = (Hh / 128) * NVT;  // 858
  const int orig = blockIdx.x;
  const int xcd = orig & 7, seq = orig >> 3;
  const int q = G >> 3, r = G & 7;
  const int lin = (xcd < r ? xcd * (q + 1) : r * (q + 1) + (xcd - r) * q) + seq;
  const int vt = lin % NVT;
  const int nb = lin / NVT;
  if (vt >= ts[Ee]) return;
  int e = 0;
#pragma unroll
  for (int i = 1; i < Ee; ++i) if (vt >= ts[i]) e = i;
  const int ne = counts[e];
  const int m0 = (vt - ts[e]) * 256;
  const int h0 = nb * 128;
  const int hb = offs[e];

  __shared__ __align__(16) bf16_t sh[2][2][16384];  // [buf][A/B][256*64] 128KB

  const int tid = threadIdx.x;
  const int lane = tid & 63;
  const int wid = tid >> 6;
  const int wm = wid >> 2, wn = wid & 3;

  const int scol = ((tid & 7) << 3) ^ (((tid >> 3) & 7) << 3);
  uint32_t aofs[4];
  const bf16_t* bsrc[4];
  {
    const bf16_t* w1e = w1t + (size_t)e * Hh * Dd;
    const bf16_t* w3e = w3t + (size_t)e * Hh * Dd;
#pragma unroll
    for (int i = 0; i < 4; ++i) {
      const int row = i * 64 + (tid >> 3);
      const int gr = m0 + row;
      const int rec = (gr < ne) ? perm[e * Tt + gr] : 0;
      aofs[i] = (uint32_t)((rec >> 1) * Dd + scol);
      bsrc[i] = (i < 2 ? w1e + (size_t)(h0 + i * 64 + (tid >> 3)) * Dd
                       : w3e + (size_t)(h0 + (i - 2) * 64 + (tid >> 3)) * Dd) + scol;
    }
  }

  f32x4 acc[8][4];
#pragma unroll
  for (int m = 0; m < 8; ++m)
#pragma unroll
    for (int n = 0; n < 4; ++n) acc[m][n] = (f32x4){0.f, 0.f, 0.f, 0.f};

  int aoffm[8], boffn[4], koff[2];
#pragma unroll
  for (int m = 0; m < 8; ++m) aoffm[m] = (wm * 128 + m * 16 + (lane & 15)) * 64;
#pragma unroll
  for (int n = 0; n < 4; ++n) boffn[n] = (wn * 64 + n * 16 + (lane & 15)) * 64;
#pragma unroll
  for (int kk = 0; kk < 2; ++kk)
    koff[kk] = (kk * 32 + (lane >> 4) * 8) ^ ((lane & 7) << 3);

  // stage one half-tile (2 x gload16/thread). h in {0,1}.
  auto stageA = [&](int b, int t, int h) {
    const int d0 = t * 64;
#pragma unroll
    for (int j = 0; j < 2; ++j)
      gload16(xb + aofs[2 * h + j] + d0, &sh[b][0][h * 8192 + j * 4096 + tid * 8]);
  };
  auto stageB = [&](int b, int t, int h) {
    const int d0 = t * 64;
#pragma unroll
    for (int j = 0; j < 2; ++j)
      gload16(bsrc[2 * h + j] + d0, &sh[b][1][h * 8192 + j * 4096 + tid * 8]);
  };

  bf16x8 a[4][2], b[4][2];
  auto rdA = [&](const bf16_t* Ac, int qm) {
#pragma unroll
    for (int mm = 0; mm < 4; ++mm)
#pragma unroll
      for (int kk = 0; kk < 2; ++kk)
        a[mm][kk] = *(const bf16x8*)(Ac + aoffm[qm * 4 + mm] + koff[kk]);
  };
  auto rdB = [&](const bf16_t* Bc, int qn) {
#pragma unroll
    for (int nn = 0; nn < 2; ++nn)
#pragma unroll
      for (int kk = 0; kk < 2; ++kk)
        b[qn * 2 + nn][kk] = *(const bf16x8*)(Bc + boffn[qn * 2 + nn] + koff[kk]);
  };
  auto quad = [&](int qm, int qn) {
    __builtin_amdgcn_s_setprio(1);
#pragma unroll
    for (int kk = 0; kk < 2; ++kk)
#pragma unroll
      for (int mm = 0; mm < 4; ++mm)
#pragma unroll
        for (int nn = 0; nn < 2; ++nn)
          acc[qm * 4 + mm][qn * 2 + nn] = __builtin_amdgcn_mfma_f32_16x16x32_bf16(
              a[mm][kk], b[qn * 2 + nn][kk], acc[qm * 4 + mm][qn * 2 + nn], 0, 0, 0);
    __builtin_amdgcn_s_setprio(0);
  };

  const int nt = Dd / 64;  // 16
  // prologue: tile0 all 4 halves, then B0,B1,A0 of tile1; confirm tile0.
  stageB(0, 0, 0); stageB(0, 0, 1); stageA(0, 0, 0); stageA(0, 0, 1);
  stageB(1, 1, 0); stageB(1, 1, 1); stageA(1, 1, 0);
  WAIT_VM(6);
  BAR();

  for (int kt = 0; kt < nt; ++kt) {
    const int c = kt & 1;
    const bf16_t* Ac = &sh[c][0][0];
    const bf16_t* Bc = &sh[c][1][0];
    // ---- p0: reads A-qm0 + B-lo; stage A1(kt+1)
    rdA(Ac, 0); rdB(Bc, 0);
    if (kt + 1 < nt) stageA(1 - c, kt + 1, 1);
    BAR();
    quad(0, 0);
    BAR();
    // ---- p1: reads B-hi
    rdB(Bc, 1);
    BAR();
    quad(0, 1);
    BAR();
    // ---- p2: reads A-qm1; stage B0(kt+2)
    rdA(Ac, 1);
    if (kt + 2 < nt) stageB(c, kt + 2, 0);
    BAR();
    quad(1, 0);
    BAR();
    // ---- p3: stage B1+A0(kt+2); confirm tile kt+1
    if (kt + 2 < nt) { stageB(c, kt + 2, 1); stageA(c, kt + 2, 0); }
    if (kt == nt - 2) { WAIT_VM(0); } else if (kt < nt - 2) { WAIT_VM(6); }
    BAR();
    quad(1, 1);
    BAR();
  }

  // epilogue: waves wn>=2 hold v3; exchange via LDS (f32, swizzled)
  __syncthreads();
  float* xch = (float*)sh;
  if (wn >= 2) {
    const int base = (wm * 2 + (wn - 2)) * 8192;
#pragma unroll
    for (int m = 0; m < 8; ++m)
#pragma unroll
      for (int n = 0; n < 4; ++n)
#pragma unroll
        for (int r2 = 0; r2 < 4; ++r2) {
          const int row = m * 16 + ((lane >> 4) << 2) + r2;
          const int col = n * 16 + (lane & 15);
          xch[base + row * 64 + (col ^ ((row & 12) << 2))] = acc[m][n][r2];
        }
  }
  __syncthreads();
  if (wn < 2) {
    const int base = (wm * 2 + wn) * 8192;
#pragma unroll
    for (int m = 0; m < 8; ++m) {
#pragma unroll
      for (int r2 = 0; r2 < 4; ++r2) {
        const int lrow = m * 16 + ((lane >> 4) << 2) + r2;
        const int gr = m0 + wm * 128 + lrow;
        if (gr >= ne) continue;
        bf16_t* orow = hbuf + (size_t)(hb + gr) * Hh + h0 + wn * 64 + (lane & 15);
#pragma unroll
        for (int n = 0; n < 4; ++n) {
          const int col = n * 16 + (lane & 15);
          const float v3 = xch[base + lrow * 64 + (col ^ ((lrow & 12) << 2))];
          const float v1 = acc[m][n][r2];
          const float s = v1 / (1.f + __expf(-v1));
          orow[n * 16] = (__bf16)(s * v3);
        }
      }
    }
  }
}

// ---------------- FFN2: o = (h @ W2) * w_slot, 256x256, K-split 2 ----------
__global__ __launch_bounds__(512, 2) void ffn2_kernel(
    const bf16_t* __restrict__ hbuf, const bf16_t* __restrict__ w2t,
    const int* __restrict__ perm, const int* __restrict__ counts,
    const int* __restrict__ offs, const int* __restrict__ ts,
    const float* __restrict__ topkw, float* __restrict__ obuf2) {
  const int G = NVT * (Dd / 256) * 2;  // 312
  const int orig = blockIdx.x;
  const int xcd = orig & 7, seq = orig >> 3;
  const int q = G >> 3, r = G & 7;
  const int lin = (xcd < r ? xcd * (q + 1) : r * (q + 1) + (xcd - r) * q) + seq;
  const int vt = lin % NVT;
  const int nb = (lin / NVT) & 3;
  const int ks = lin / (NVT * 4);
  if (vt >= ts[Ee]) return;
  int e = 0;
#pragma unroll
  for (int i = 1; i < Ee; ++i) if (vt >= ts[i]) e = i;
  const int ne = counts[e];
  const int m0 = (vt - ts[e]) * 256;
  const int n0 = nb * 256;
  const int hb = offs[e];

  __shared__ __align__(16) bf16_t sh[2][2][16384];

  const int tid = threadIdx.x;
  const int lane = tid & 63;
  const int wid = tid >> 6;
  const int wm = wid >> 2, wn = wid & 3;

  const int scol = ((tid & 7) << 3) ^ (((tid >> 3) & 7) << 3);
  uint32_t aofs[4], bofs[4];
  {
#pragma unroll
    for (int i = 0; i < 4; ++i) {
      const int row = i * 64 + (tid >> 3);
      int ar = hb + m0 + row;
      if (ar > 2 * Tt - 1) ar = 2 * Tt - 1;
      aofs[i] = (uint32_t)(ar * Hh + scol);
      bofs[i] = (uint32_t)((n0 + row) * Hh + scol);
    }
  }
  const bf16_t* w2e = w2t + (size_t)e * Dd * Hh;

  f32x4 acc[8][4];
#pragma unroll
  for (int m = 0; m < 8; ++m)
#pragma unroll
    for (int n = 0; n < 4; ++n) acc[m][n] = (f32x4){0.f, 0.f, 0.f, 0.f};

  int aoffm[8], boffn[4], koff[2];
#pragma unroll
  for (int m = 0; m < 8; ++m) aoffm[m] = (wm * 128 + m * 16 + (lane & 15)) * 64;
#pragma unroll
  for (int n = 0; n < 4; ++n) boffn[n] = (wn * 64 + n * 16 + (lane & 15)) * 64;
#pragma unroll
  for (int kk = 0; kk < 2; ++kk)
    koff[kk] = (kk * 32 + (lane >> 4) * 8) ^ ((lane & 7) << 3);

  const int nt = (Hh / 64) / 2;  // 22
  const int kbase = ks * nt;
  auto stageA = [&](int b, int t, int h) {
    const int k0 = (kbase + t) * 64;
#pragma unroll
    for (int j = 0; j < 2; ++j)
      gload16(hbuf + aofs[2 * h + j] + k0, &sh[b][0][h * 8192 + j * 4096 + tid * 8]);
  };
  auto stageB = [&](int b, int t, int h) {
    const int k0 = (kbase + t) * 64;
#pragma unroll
    for (int j = 0; j < 2; ++j)
      gload16(w2e + bofs[2 * h + j] + k0, &sh[b][1][h * 8192 + j * 4096 + tid * 8]);
  };

  bf16x8 a[4][2], b[4][2];
  auto rdA = [&](const bf16_t* Ac, int qm) {
#pragma unroll
    for (int mm = 0; mm < 4; ++mm)
#pragma unroll
      for (int kk = 0; kk < 2; ++kk)
        a[mm][kk] = *(const bf16x8*)(Ac + aoffm[qm * 4 + mm] + koff[kk]);
  };
  auto rdB = [&](const bf16_t* Bc, int qn) {
#pragma unroll
    for (int nn = 0; nn < 2; ++nn)
#pragma unroll
      for (int kk = 0; kk < 2; ++kk)
        b[qn * 2 + nn][kk] = *(const bf16x8*)(Bc + boffn[qn * 2 + nn] + koff[kk]);
  };
  auto quad = [&](int qm, int qn) {
    __builtin_amdgcn_s_setprio(1);
#pragma unroll
    for (int kk = 0; kk < 2; ++kk)
#pragma unroll
      for (int mm = 0; mm < 4; ++mm)
#pragma unroll
        for (int nn = 0; nn < 2; ++nn)
          acc[qm * 4 + mm][qn * 2 + nn] = __builtin_amdgcn_mfma_f32_16x16x32_bf16(
              a[mm][kk], b[qn * 2 + nn][kk], acc[qm * 4 + mm][qn * 2 + nn], 0, 0, 0);
    __builtin_amdgcn_s_setprio(0);
  };

  stageB(0, 0, 0); stageB(0, 0, 1); stageA(0, 0, 0); stageA(0, 0, 1);
  stageB(1, 1, 0); stageB(1, 1, 1); stageA(1, 1, 0);
  WAIT_VM(6);
  BAR();

  for (int kt = 0; kt < nt; ++kt) {
    const int c = kt & 1;
    const bf16_t* Ac = &sh[c][0][0];
    const bf16_t* Bc = &sh[c][1][0];
    rdA(Ac, 0); rdB(Bc, 0);
    if (kt + 1 < nt) stageA(1 - c, kt + 1, 1);
    BAR();
    quad(0, 0);
    BAR();
    rdB(Bc, 1);
    BAR();
    quad(0, 1);
    BAR();
    rdA(Ac, 1);
    if (kt + 2 < nt) stageB(c, kt + 2, 0);
    BAR();
    quad(1, 0);
    BAR();
    if (kt + 2 < nt) { stageB(c, kt + 2, 1); stageA(c, kt + 2, 0); }
    if (kt == nt - 2) { WAIT_VM(0); } else if (kt < nt - 2) { WAIT_VM(6); }
    BAR();
    quad(1, 1);
    BAR();
  }

  float* oslice = obuf2 + (size_t)ks * 2 * Tt * Dd;
#pragma unroll
  for (int m = 0; m < 8; ++m) {
#pragma unroll
    for (int r2 = 0; r2 < 4; ++r2) {
      const int gr = m0 + wm * 128 + m * 16 + ((lane >> 4) << 2) + r2;
      if (gr >= ne) continue;
      const int rec = perm[e * Tt + gr];
      const float wgt = topkw[rec];
      float* orow = oslice + (size_t)rec * Dd + n0 + wn * 64 + (lane & 15);
#pragma unroll
      for (int n = 0; n < 4; ++n) orow[n * 16] = wgt * acc[m][n][r2];
    }
  }
}

// ---------------- combine: out[t] = sum over 2 slots x 2 K-slices ----------
__global__ __launch_bounds__(256) void combine_kernel(const float* __restrict__ obuf2,
                                                      float* __restrict__ out) {
  const int t = blockIdx.x;
  const int d = threadIdx.x * 4;
  const float* s0 = obuf2;
  const float* s1 = obuf2 + (size_t)2 * Tt * Dd;
  const float4 a = *(const float4*)(s0 + (size_t)(2 * t) * Dd + d);
  const float4 b = *(const float4*)(s0 + (size_t)(2 * t + 1) * Dd + d);
  const float4 c = *(const float4*)(s1 + (size_t)(2 * t) * Dd + d);
  const float4 e = *(const float4*)(s1 + (size_t)(2 * t + 1) * Dd + d);
  float4 o;
  o.x = a.x + b.x + c.x + e.x; o.y = a.y + b.y + c.y + e.y;
  o.z = a.z + b.z + c.z + e.z; o.w = a.w + b.w + c.w + e.w;
  *(float4*)(out + (size_t)t * Dd + d) = o;
}

extern "C" void kernel_launch(void* const* d_in, const int* in_sizes, int n_in,
                              void* d_out, int out_size, void* d_ws, size_t ws_size,
                              hipStream_t stream) {
  const float* x = (const float*)d_in[0];
  const float* gate_w = (const float*)d_in[1];
  const float* w1 = (const float*)d_in[2];
  const float* w2 = (const float*)d_in[3];
  const float* w3 = (const float*)d_in[4];
  float* out = (float*)d_out;

  char* ws = (char*)d_ws;
  size_t off = 0;
  auto alloc = [&](size_t b) { size_t r = off; off += (b + 255) & ~(size_t)255; return r; };
  float* topkw   = (float*)(ws + alloc((size_t)Tt * 2 * 4));
  int* counts    = (int*)(ws + alloc(Ee * 4));
  int* offs      = (int*)(ws + alloc((Ee + 1) * 4));
  int* ts        = (int*)(ws + alloc((Ee + 1) * 4));
  int* perm      = (int*)(ws + alloc((size_t)Ee * Tt * 4));
  bf16_t* xb     = (bf16_t*)(ws + alloc((size_t)Tt * Dd * 2));
  const size_t w1t_off = alloc((size_t)Ee * Hh * Dd * 2);
  bf16_t* w1t    = (bf16_t*)(ws + w1t_off);
  bf16_t* w3t    = (bf16_t*)(ws + alloc((size_t)Ee * Hh * Dd * 2));
  bf16_t* w2t    = (bf16_t*)(ws + alloc((size_t)Ee * Dd * Hh * 2));
  bf16_t* hbuf   = (bf16_t*)(ws + alloc((size_t)Tt * 2 * Hh * 2));
  // obuf2 (2 x 8192 x 1024 f32 = 64MB) aliases dead w1t+w3t (92MB)
  float* obuf2   = (float*)(ws + w1t_off);
  if (ws_size < off) return;

  hipMemsetAsync(counts, 0, Ee * 4, stream);
  gate_kernel<<<Tt / 32, 256, 0, stream>>>(x, gate_w, counts, perm, topkw, xb);
  scan_kernel<<<1, 64, 0, stream>>>(counts, offs, ts);
  prep_w_kernel<<<3 * Ee * (Dd / 64) * (Hh / 64), 256, 0, stream>>>(w1, w3, w2, w1t, w3t, w2t);
  ffn1_kernel<<<(Hh / 128) * NVT, 512, 0, stream>>>(xb, w1t, w3t, perm, counts, offs, ts, hbuf);
  ffn2_kernel<<<NVT * (Dd / 256) * 2, 512, 0, stream>>>(hbuf, w2t, perm, counts, offs, ts, topkw, obuf2);
  combine_kernel<<<Tt, 256, 0, stream>>>(obuf2, out);
}

// Round 6
// 361.582 us; speedup vs baseline: 1.0336x; 1.0336x over previous
//
#include <hip/hip_runtime.h>
#include <hip/hip_bf16.h>
#include <cstdint>
#include <cstddef>

// MoE: T=4096, D=1024, H=2816, E=8, top-2, SwiGLU.
// R6: occupancy-first. Three m97-style GEMMs (128x128, BK=64, 4 waves,
//     64x64/wave, acc=64 AGPR, 32KB LDS, plain 2-barrier loop,
//     launch_bounds(256,3) -> 3 waves/SIMD, 3 blocks/CU cross-block overlap):
//     gemm1: g1 = silu(X@W1); gemm2: hbuf = (X@W3)*g1; ffn2: obuf = h@W2*wgt.

#define Tt 4096
#define Dd 1024
#define Hh 2816
#define Ee 8
#define NVT 71  // max sum_e ceil(ne/128)

typedef __bf16 bf16_t;
typedef __bf16 bf16x4 __attribute__((ext_vector_type(4)));
typedef __bf16 bf16x8 __attribute__((ext_vector_type(8)));
typedef float f32x4 __attribute__((ext_vector_type(4)));

__device__ __forceinline__ void gload16(const void* g, void* l) {
  __builtin_amdgcn_global_load_lds(
      (__attribute__((address_space(1))) void*)(void*)(uintptr_t)g,
      (__attribute__((address_space(3))) void*)l, 16, 0, 0);
}
#define WAIT_VM0() asm volatile("s_waitcnt vmcnt(0)" ::: "memory")

// ---------------- gate: fp32 logits, top-2, softmax, routing, + x->bf16 -----
__global__ __launch_bounds__(256) void gate_kernel(
    const float* __restrict__ x, const float* __restrict__ gw_g,
    int* __restrict__ counts, int* __restrict__ perm, float* __restrict__ topkw,
    bf16_t* __restrict__ xb) {
  __shared__ float gw[Dd * 9];
  const int tid = threadIdx.x;
  for (int i = tid; i < Dd * Ee; i += 256) gw[(i >> 3) * 9 + (i & 7)] = gw_g[i];
  __syncthreads();
  const int tok = blockIdx.x * 32 + (tid >> 3);
  const int part = tid & 7;
  const float* xr = x + (size_t)tok * Dd;
  float acc[Ee];
#pragma unroll
  for (int e = 0; e < Ee; ++e) acc[e] = 0.f;
  for (int i = 0; i < 32; ++i) {
    const int d = i * 32 + part * 4;
    const float4 xv = *(const float4*)(xr + d);
    bf16x4 bv; bv[0] = (__bf16)xv.x; bv[1] = (__bf16)xv.y; bv[2] = (__bf16)xv.z; bv[3] = (__bf16)xv.w;
    *(bf16x4*)(xb + (size_t)tok * Dd + d) = bv;
    const float xs[4] = {xv.x, xv.y, xv.z, xv.w};
#pragma unroll
    for (int j = 0; j < 4; ++j)
#pragma unroll
      for (int e = 0; e < Ee; ++e) acc[e] += xs[j] * gw[(d + j) * 9 + e];
  }
#pragma unroll
  for (int s = 1; s < 8; s <<= 1)
#pragma unroll
    for (int e = 0; e < Ee; ++e) acc[e] += __shfl_xor(acc[e], s, 64);
  if (part == 0) {
    int i0 = 0; float v0 = acc[0];
#pragma unroll
    for (int e = 1; e < Ee; ++e) if (acc[e] > v0) { v0 = acc[e]; i0 = e; }
    int i1 = -1; float v1 = -1e30f;
#pragma unroll
    for (int e = 0; e < Ee; ++e)
      if (e != i0 && acc[e] > v1) { v1 = acc[e]; i1 = e; }
    const float w0 = 1.f / (1.f + __expf(v1 - v0));
    topkw[tok * 2 + 0] = w0;
    topkw[tok * 2 + 1] = 1.f - w0;
    const int p0 = atomicAdd(&counts[i0], 1);
    perm[i0 * Tt + p0] = tok * 2 + 0;
    const int p1 = atomicAdd(&counts[i1], 1);
    perm[i1 * Tt + p1] = tok * 2 + 1;
  }
}

__global__ void scan_kernel(const int* __restrict__ counts, int* __restrict__ offs,
                            int* __restrict__ ts) {
  if (threadIdx.x == 0) {
    int s = 0, t = 0;
    for (int e = 0; e < Ee; ++e) {
      offs[e] = s; ts[e] = t;
      s += counts[e]; t += (counts[e] + 127) >> 7;
    }
    offs[Ee] = s; ts[Ee] = t;
  }
}

// ---------------- transpose + cast weights to bf16 (k-contiguous) ----------
__global__ __launch_bounds__(256) void prep_w_kernel(
    const float* __restrict__ w1, const float* __restrict__ w3,
    const float* __restrict__ w2, bf16_t* __restrict__ w1t,
    bf16_t* __restrict__ w3t, bf16_t* __restrict__ w2t) {
  int bid = blockIdx.x;
  const int ntile = Ee * (Dd / 64) * (Hh / 64);
  const float* src; bf16_t* dst; int R, C;
  if (bid < ntile) { src = w1; dst = w1t; R = Dd; C = Hh; }
  else if (bid < 2 * ntile) { src = w3; dst = w3t; R = Dd; C = Hh; bid -= ntile; }
  else { src = w2; dst = w2t; R = Hh; C = Dd; bid -= 2 * ntile; }
  const int tilesC = C / 64, tilesR = R / 64;
  const int e = bid / (tilesR * tilesC);
  const int rem = bid % (tilesR * tilesC);
  const int r0 = (rem / tilesC) * 64, c0 = (rem % tilesC) * 64;
  src += (size_t)e * R * C;
  dst += (size_t)e * R * C;

  __shared__ bf16_t tile[64 * 68];
  const int tid = threadIdx.x;
#pragma unroll
  for (int i = 0; i < 16; ++i) {
    const int r = (tid >> 6) + i * 4;
    const int c = tid & 63;
    tile[c * 68 + r] = (__bf16)src[(size_t)(r0 + r) * C + c0 + c];
  }
  __syncthreads();
#pragma unroll
  for (int i = 0; i < 4; ++i) {
    const int c = i * 16 + (tid >> 4);
    const int rch = (tid & 15) * 4;
    uint2 val;
    val.x = *(const uint32_t*)(tile + c * 68 + rch);
    val.y = *(const uint32_t*)(tile + c * 68 + rch + 2);
    *(uint2*)(dst + (size_t)(c0 + c) * R + r0 + rch) = val;
  }
}

// ======================= m97-style GEMM core (macro-ish) ====================
// 128x128 tile, BK=64, 4 waves (2x2), per-wave 64x64 (acc[4][4] = 64 AGPR).
// Plain loop: sync; stage 8x gload16; vmcnt(0); sync; 2xkk{reads; 16 MFMA}.

// ---------------- gemm1: g1 = silu(Xg @ W1^T) -------------------------------
__global__ __launch_bounds__(256, 3) void gemm1_kernel(
    const bf16_t* __restrict__ xb, const bf16_t* __restrict__ w1t,
    const int* __restrict__ perm, const int* __restrict__ counts,
    const int* __restrict__ offs, const int* __restrict__ ts,
    bf16_t* __restrict__ g1) {
  const int G = (Hh / 128) * NVT;  // 1562
  const int orig = blockIdx.x;
  const int xcd = orig & 7, seq = orig >> 3;
  const int q = G >> 3, r = G & 7;  // 195, 2
  const int lin = (xcd < r ? xcd * (q + 1) : r * (q + 1) + (xcd - r) * q) + seq;
  const int vt = lin % NVT;
  const int nb = lin / NVT;
  if (vt >= ts[Ee]) return;
  int e = 0;
#pragma unroll
  for (int i = 1; i < Ee; ++i) if (vt >= ts[i]) e = i;
  const int ne = counts[e];
  const int m0 = (vt - ts[e]) * 128;
  const int h0 = nb * 128;
  const int hb = offs[e];

  __shared__ __align__(16) bf16_t As[128 * 64];
  __shared__ __align__(16) bf16_t Bs[128 * 64];

  const int tid = threadIdx.x;
  const int lane = tid & 63;
  const int wid = tid >> 6;
  const int scol = ((tid & 7) << 3) ^ (((tid >> 3) & 7) << 3);
  uint32_t aoff[4], boff[4];
#pragma unroll
  for (int i = 0; i < 4; ++i) {
    const int row = i * 32 + (tid >> 3);
    const int gr = m0 + row;
    const int rec = (gr < ne) ? perm[e * Tt + gr] : 0;
    aoff[i] = (uint32_t)((rec >> 1) * Dd + scol);
    boff[i] = (uint32_t)((h0 + row) * Dd + scol);
  }
  const bf16_t* w1e = w1t + (size_t)e * Hh * Dd;

  f32x4 acc[4][4];
#pragma unroll
  for (int m = 0; m < 4; ++m)
#pragma unroll
    for (int n = 0; n < 4; ++n) acc[m][n] = (f32x4){0.f, 0.f, 0.f, 0.f};

  const int wm = wid >> 1, wn = wid & 1;
  int aoffm[4], boffn[4], koff[2];
#pragma unroll
  for (int m = 0; m < 4; ++m) aoffm[m] = (wm * 64 + m * 16 + (lane & 15)) * 64;
#pragma unroll
  for (int n = 0; n < 4; ++n) boffn[n] = (wn * 64 + n * 16 + (lane & 15)) * 64;
#pragma unroll
  for (int kk = 0; kk < 2; ++kk)
    koff[kk] = (kk * 32 + (lane >> 4) * 8) ^ ((lane & 7) << 3);

  for (int kt = 0; kt < Dd / 64; ++kt) {
    const int d0 = kt * 64;
    __syncthreads();
#pragma unroll
    for (int i = 0; i < 4; ++i) {
      const int lb = (i * 256 + tid) * 8;
      gload16(xb + aoff[i] + d0, As + lb);
      gload16(w1e + boff[i] + d0, Bs + lb);
    }
    WAIT_VM0();
    __syncthreads();
#pragma unroll
    for (int kk = 0; kk < 2; ++kk) {
      bf16x8 a[4], b[4];
#pragma unroll
      for (int m = 0; m < 4; ++m) a[m] = *(const bf16x8*)(As + aoffm[m] + koff[kk]);
#pragma unroll
      for (int n = 0; n < 4; ++n) b[n] = *(const bf16x8*)(Bs + boffn[n] + koff[kk]);
#pragma unroll
      for (int m = 0; m < 4; ++m)
#pragma unroll
        for (int n = 0; n < 4; ++n)
          acc[m][n] = __builtin_amdgcn_mfma_f32_16x16x32_bf16(a[m], b[n], acc[m][n], 0, 0, 0);
    }
  }

#pragma unroll
  for (int m = 0; m < 4; ++m) {
    const int rb = m0 + wm * 64 + m * 16 + ((lane >> 4) << 2);
#pragma unroll
    for (int r2 = 0; r2 < 4; ++r2) {
      const int gr = rb + r2;
      if (gr >= ne) continue;
      bf16_t* orow = g1 + (size_t)(hb + gr) * Hh + h0 + wn * 64 + (lane & 15);
#pragma unroll
      for (int n = 0; n < 4; ++n) {
        const float v1 = acc[m][n][r2];
        orow[n * 16] = (__bf16)(v1 / (1.f + __expf(-v1)));
      }
    }
  }
}

// ---------------- gemm2: hbuf = (Xg @ W3^T) * g1 ----------------------------
__global__ __launch_bounds__(256, 3) void gemm2_kernel(
    const bf16_t* __restrict__ xb, const bf16_t* __restrict__ w3t,
    const int* __restrict__ perm, const int* __restrict__ counts,
    const int* __restrict__ offs, const int* __restrict__ ts,
    const bf16_t* __restrict__ g1, bf16_t* __restrict__ hbuf) {
  const int G = (Hh / 128) * NVT;
  const int orig = blockIdx.x;
  const int xcd = orig & 7, seq = orig >> 3;
  const int q = G >> 3, r = G & 7;
  const int lin = (xcd < r ? xcd * (q + 1) : r * (q + 1) + (xcd - r) * q) + seq;
  const int vt = lin % NVT;
  const int nb = lin / NVT;
  if (vt >= ts[Ee]) return;
  int e = 0;
#pragma unroll
  for (int i = 1; i < Ee; ++i) if (vt >= ts[i]) e = i;
  const int ne = counts[e];
  const int m0 = (vt - ts[e]) * 128;
  const int h0 = nb * 128;
  const int hb = offs[e];

  __shared__ __align__(16) bf16_t As[128 * 64];
  __shared__ __align__(16) bf16_t Bs[128 * 64];

  const int tid = threadIdx.x;
  const int lane = tid & 63;
  const int wid = tid >> 6;
  const int scol = ((tid & 7) << 3) ^ (((tid >> 3) & 7) << 3);
  uint32_t aoff[4], boff[4];
#pragma unroll
  for (int i = 0; i < 4; ++i) {
    const int row = i * 32 + (tid >> 3);
    const int gr = m0 + row;
    const int rec = (gr < ne) ? perm[e * Tt + gr] : 0;
    aoff[i] = (uint32_t)((rec >> 1) * Dd + scol);
    boff[i] = (uint32_t)((h0 + row) * Dd + scol);
  }
  const bf16_t* w3e = w3t + (size_t)e * Hh * Dd;

  f32x4 acc[4][4];
#pragma unroll
  for (int m = 0; m < 4; ++m)
#pragma unroll
    for (int n = 0; n < 4; ++n) acc[m][n] = (f32x4){0.f, 0.f, 0.f, 0.f};

  const int wm = wid >> 1, wn = wid & 1;
  int aoffm[4], boffn[4], koff[2];
#pragma unroll
  for (int m = 0; m < 4; ++m) aoffm[m] = (wm * 64 + m * 16 + (lane & 15)) * 64;
#pragma unroll
  for (int n = 0; n < 4; ++n) boffn[n] = (wn * 64 + n * 16 + (lane & 15)) * 64;
#pragma unroll
  for (int kk = 0; kk < 2; ++kk)
    koff[kk] = (kk * 32 + (lane >> 4) * 8) ^ ((lane & 7) << 3);

  for (int kt = 0; kt < Dd / 64; ++kt) {
    const int d0 = kt * 64;
    __syncthreads();
#pragma unroll
    for (int i = 0; i < 4; ++i) {
      const int lb = (i * 256 + tid) * 8;
      gload16(xb + aoff[i] + d0, As + lb);
      gload16(w3e + boff[i] + d0, Bs + lb);
    }
    WAIT_VM0();
    __syncthreads();
#pragma unroll
    for (int kk = 0; kk < 2; ++kk) {
      bf16x8 a[4], b[4];
#pragma unroll
      for (int m = 0; m < 4; ++m) a[m] = *(const bf16x8*)(As + aoffm[m] + koff[kk]);
#pragma unroll
      for (int n = 0; n < 4; ++n) b[n] = *(const bf16x8*)(Bs + boffn[n] + koff[kk]);
#pragma unroll
      for (int m = 0; m < 4; ++m)
#pragma unroll
        for (int n = 0; n < 4; ++n)
          acc[m][n] = __builtin_amdgcn_mfma_f32_16x16x32_bf16(a[m], b[n], acc[m][n], 0, 0, 0);
    }
  }

#pragma unroll
  for (int m = 0; m < 4; ++m) {
    const int rb = m0 + wm * 64 + m * 16 + ((lane >> 4) << 2);
#pragma unroll
    for (int r2 = 0; r2 < 4; ++r2) {
      const int gr = rb + r2;
      if (gr >= ne) continue;
      const size_t rowb = (size_t)(hb + gr) * Hh + h0 + wn * 64 + (lane & 15);
      const bf16_t* grow = g1 + rowb;
      bf16_t* hrow = hbuf + rowb;
#pragma unroll
      for (int n = 0; n < 4; ++n) {
        const float v3 = acc[m][n][r2];
        const float s = (float)grow[n * 16];
        hrow[n * 16] = (__bf16)(s * v3);
      }
    }
  }
}

// ---------------- ffn2: obuf = (hbuf @ W2^T) * w_slot -----------------------
__global__ __launch_bounds__(256, 3) void ffn2_kernel(
    const bf16_t* __restrict__ hbuf, const bf16_t* __restrict__ w2t,
    const int* __restrict__ perm, const int* __restrict__ counts,
    const int* __restrict__ offs, const int* __restrict__ ts,
    const float* __restrict__ topkw, float* __restrict__ obuf) {
  const int G = (Dd / 128) * NVT;  // 568
  const int orig = blockIdx.x;
  const int xcd = orig & 7, seq = orig >> 3;
  const int q = G >> 3, r = G & 7;  // 71, 0
  const int lin = (xcd < r ? xcd * (q + 1) : r * (q + 1) + (xcd - r) * q) + seq;
  const int vt = lin % NVT;
  const int nb = lin / NVT;
  if (vt >= ts[Ee]) return;
  int e = 0;
#pragma unroll
  for (int i = 1; i < Ee; ++i) if (vt >= ts[i]) e = i;
  const int ne = counts[e];
  const int m0 = (vt - ts[e]) * 128;
  const int n0 = nb * 128;
  const int hb = offs[e];

  __shared__ __align__(16) bf16_t As[128 * 64];
  __shared__ __align__(16) bf16_t Bs[128 * 64];

  const int tid = threadIdx.x;
  const int lane = tid & 63;
  const int wid = tid >> 6;
  const int scol = ((tid & 7) << 3) ^ (((tid >> 3) & 7) << 3);
  uint32_t aoff[4], boff[4];
#pragma unroll
  for (int i = 0; i < 4; ++i) {
    const int row = i * 32 + (tid >> 3);
    int ar = hb + m0 + row;
    if (ar > 2 * Tt - 1) ar = 2 * Tt - 1;
    aoff[i] = (uint32_t)(ar * Hh + scol);
    boff[i] = (uint32_t)((n0 + row) * Hh + scol);
  }
  const bf16_t* w2e = w2t + (size_t)e * Dd * Hh;

  f32x4 acc[4][4];
#pragma unroll
  for (int m = 0; m < 4; ++m)
#pragma unroll
    for (int n = 0; n < 4; ++n) acc[m][n] = (f32x4){0.f, 0.f, 0.f, 0.f};

  const int wm = wid >> 1, wn = wid & 1;
  int aoffm[4], boffn[4], koff[2];
#pragma unroll
  for (int m = 0; m < 4; ++m) aoffm[m] = (wm * 64 + m * 16 + (lane & 15)) * 64;
#pragma unroll
  for (int n = 0; n < 4; ++n) boffn[n] = (wn * 64 + n * 16 + (lane & 15)) * 64;
#pragma unroll
  for (int kk = 0; kk < 2; ++kk)
    koff[kk] = (kk * 32 + (lane >> 4) * 8) ^ ((lane & 7) << 3);

  for (int kt = 0; kt < Hh / 64; ++kt) {
    const int k0 = kt * 64;
    __syncthreads();
#pragma unroll
    for (int i = 0; i < 4; ++i) {
      const int lb = (i * 256 + tid) * 8;
      gload16(hbuf + aoff[i] + k0, As + lb);
      gload16(w2e + boff[i] + k0, Bs + lb);
    }
    WAIT_VM0();
    __syncthreads();
#pragma unroll
    for (int kk = 0; kk < 2; ++kk) {
      bf16x8 a[4], b[4];
#pragma unroll
      for (int m = 0; m < 4; ++m) a[m] = *(const bf16x8*)(As + aoffm[m] + koff[kk]);
#pragma unroll
      for (int n = 0; n < 4; ++n) b[n] = *(const bf16x8*)(Bs + boffn[n] + koff[kk]);
#pragma unroll
      for (int m = 0; m < 4; ++m)
#pragma unroll
        for (int n = 0; n < 4; ++n)
          acc[m][n] = __builtin_amdgcn_mfma_f32_16x16x32_bf16(a[m], b[n], acc[m][n], 0, 0, 0);
    }
  }

#pragma unroll
  for (int m = 0; m < 4; ++m) {
    const int rb = m0 + wm * 64 + m * 16 + ((lane >> 4) << 2);
#pragma unroll
    for (int r2 = 0; r2 < 4; ++r2) {
      const int gr = rb + r2;
      if (gr >= ne) continue;
      const int rec = perm[e * Tt + gr];
      const float wgt = topkw[rec];
      float* orow = obuf + (size_t)rec * Dd + n0 + wn * 64 + (lane & 15);
#pragma unroll
      for (int n = 0; n < 4; ++n) orow[n * 16] = wgt * acc[m][n][r2];
    }
  }
}

// ---------------- combine: out[t] = obuf[2t] + obuf[2t+1] -------------------
__global__ __launch_bounds__(256) void combine_kernel(const float* __restrict__ obuf,
                                                      float* __restrict__ out) {
  const int t = blockIdx.x;
  const int d = threadIdx.x * 4;
  const float4 a = *(const float4*)(obuf + (size_t)(2 * t) * Dd + d);
  const float4 b = *(const float4*)(obuf + (size_t)(2 * t + 1) * Dd + d);
  float4 o;
  o.x = a.x + b.x; o.y = a.y + b.y; o.z = a.z + b.z; o.w = a.w + b.w;
  *(float4*)(out + (size_t)t * Dd + d) = o;
}

extern "C" void kernel_launch(void* const* d_in, const int* in_sizes, int n_in,
                              void* d_out, int out_size, void* d_ws, size_t ws_size,
                              hipStream_t stream) {
  const float* x = (const float*)d_in[0];
  const float* gate_w = (const float*)d_in[1];
  const float* w1 = (const float*)d_in[2];
  const float* w2 = (const float*)d_in[3];
  const float* w3 = (const float*)d_in[4];
  float* out = (float*)d_out;

  char* ws = (char*)d_ws;
  size_t off = 0;
  auto alloc = [&](size_t b) { size_t r = off; off += (b + 255) & ~(size_t)255; return r; };
  float* topkw   = (float*)(ws + alloc((size_t)Tt * 2 * 4));
  int* counts    = (int*)(ws + alloc(Ee * 4));
  int* offs      = (int*)(ws + alloc((Ee + 1) * 4));
  int* ts        = (int*)(ws + alloc((Ee + 1) * 4));
  int* perm      = (int*)(ws + alloc((size_t)Ee * Tt * 4));
  bf16_t* xb     = (bf16_t*)(ws + alloc((size_t)Tt * Dd * 2));
  const size_t w1t_off = alloc((size_t)Ee * Hh * Dd * 2);
  bf16_t* w1t    = (bf16_t*)(ws + w1t_off);
  bf16_t* w3t    = (bf16_t*)(ws + alloc((size_t)Ee * Hh * Dd * 2));
  bf16_t* w2t    = (bf16_t*)(ws + alloc((size_t)Ee * Dd * Hh * 2));
  const size_t g1_off = alloc((size_t)Tt * 2 * Hh * 2);
  bf16_t* g1     = (bf16_t*)(ws + g1_off);
  // lifetime aliases: hbuf (46MB) over dead w1t; obuf (32MB) over dead g1
  bf16_t* hbuf   = (bf16_t*)(ws + w1t_off);
  float* obuf    = (float*)(ws + g1_off);
  if (ws_size < off) return;

  hipMemsetAsync(counts, 0, Ee * 4, stream);
  gate_kernel<<<Tt / 32, 256, 0, stream>>>(x, gate_w, counts, perm, topkw, xb);
  scan_kernel<<<1, 64, 0, stream>>>(counts, offs, ts);
  prep_w_kernel<<<3 * Ee * (Dd / 64) * (Hh / 64), 256, 0, stream>>>(w1, w3, w2, w1t, w3t, w2t);
  gemm1_kernel<<<(Hh / 128) * NVT, 256, 0, stream>>>(xb, w1t, perm, counts, offs, ts, g1);
  gemm2_kernel<<<(Hh / 128) * NVT, 256, 0, stream>>>(xb, w3t, perm, counts, offs, ts, g1, hbuf);
  ffn2_kernel<<<(Dd / 128) * NVT, 256, 0, stream>>>(hbuf, w2t, perm, counts, offs, ts, topkw, obuf);
  combine_kernel<<<Tt, 256, 0, stream>>>(obuf, out);
}